// Round 10
// baseline (991.360 us; speedup 1.0000x reference)
//
#include <hip/hip_runtime.h>
#include <hip/hip_bf16.h>
#include <stdint.h>

using bf16x8 = __attribute__((ext_vector_type(8))) short;
using f32x4  = __attribute__((ext_vector_type(4))) float;

#define BATCH 64
#define NTOK  4096
#define HD    256
#define HDIM  1024
#define GD    512

__device__ __forceinline__ ushort f2bf(float f) {
  union { __hip_bfloat16 h; ushort u; } cv;
  cv.h = __float2bfloat16(f);
  return cv.u;
}

__device__ __forceinline__ void gload_lds16(const void* gsrc, void* ldst) {
  typedef const __attribute__((address_space(1))) uint32_t* gas_p;
  typedef __attribute__((address_space(3))) uint32_t* las_p;
  __builtin_amdgcn_global_load_lds((gas_p)(uintptr_t)gsrc, (las_p)(uintptr_t)ldst, 16, 0, 0);
}

struct WTArgs {
  const float* src[6];
  ushort* dst[6];
  int fi[6];
  int fo[6];
};

// ---- merged pre-pass: blocks [0,64) = bucket per batch; rest = weight transposes ----
__global__ __launch_bounds__(256) void pre_kernel(WTArgs a,
                                                  const int* __restrict__ cs,
                                                  const int* __restrict__ nptr,
                                                  int* __restrict__ idx,
                                                  int* __restrict__ off,
                                                  int* __restrict__ cnt,
                                                  int* __restrict__ Ks,
                                                  int K) {
  __shared__ int csb[NTOK];
  __shared__ ushort hist[256 * 32];
  __shared__ int segsum[8][32];
  __shared__ int btot[32];
  __shared__ int bbase[32];
  __shared__ int red[4];
  __shared__ float tile[32][33];
  int t = threadIdx.x;
  if (blockIdx.x < BATCH) {
    int b = blockIdx.x;
    int n = *nptr;
    const int* csrow = cs + (size_t)b * NTOK;
    int mymax = -1;
    for (int i = t; i < n; i += 256) { int v = csrow[i]; csb[i] = v; mymax = max(mymax, v); }
#pragma unroll
    for (int k = 0; k < 32; ++k) hist[t * 32 + k] = 0;
    __syncthreads();
    int chunkN = (n + 255) >> 8;
    for (int c = 0; c < chunkN; ++c) {
      int i = c * 256 + t;
      if (i < n) hist[t * 32 + csb[i]]++;
    }
    __syncthreads();
    int kb = t & 31, sg = t >> 5;
    {
      int run = 0;
      int r0 = sg * 32;
      for (int r = r0; r < r0 + 32; ++r) run += hist[r * 32 + kb];
      segsum[sg][kb] = run;
    }
    __syncthreads();
    if (t < 32) {
      int acc0 = 0;
      for (int s = 0; s < 8; ++s) { int v = segsum[s][t]; segsum[s][t] = acc0; acc0 += v; }
      btot[t] = acc0;
    }
    __syncthreads();
    {
      int run = segsum[sg][kb];
      int r0 = sg * 32;
      for (int r = r0; r < r0 + 32; ++r) {
        int tmp = hist[r * 32 + kb];
        hist[r * 32 + kb] = (ushort)run;
        run += tmp;
      }
    }
    if (t == 0) {
      int base = 0;
      for (int k = 0; k < K; ++k) { bbase[k] = base; base += btot[k]; }
    }
    __syncthreads();
    if (t < K) { off[b * K + t] = bbase[t]; cnt[b * K + t] = btot[t]; }
    int* idxb = idx + (size_t)b * NTOK;
    for (int c = 0; c < chunkN; ++c) {
      int i = c * 256 + t;
      if (i < n) {
        int k = csb[i];
        int s = bbase[k] + (int)(hist[t * 32 + k]++);
        idxb[s] = i;
      }
    }
    for (int o2 = 32; o2; o2 >>= 1) mymax = max(mymax, __shfl_down(mymax, o2));
    if ((t & 63) == 0) red[t >> 6] = mymax;
    __syncthreads();
    if (t == 0) {
      int r = red[0];
      for (int i = 1; i < 4; ++i) r = max(r, red[i]);
      Ks[b] = r;
    }
  } else {
    int f = blockIdx.x - BATCH;
    int z = 0;
    while (true) {
      int nb = (a.fo[z] >> 5) * (a.fi[z] >> 5);
      if (f < nb) break;
      f -= nb; ++z;
    }
    int ncx = a.fo[z] >> 5;
    int cx = f % ncx, cy = f / ncx;
    int c0 = cx * 32, r0 = cy * 32;
    int fo = a.fo[z], fi = a.fi[z];
    const float* W = a.src[z];
    ushort* Wt = a.dst[z];
    int tx = t & 31, ty = t >> 5;
#pragma unroll
    for (int j = 0; j < 4; ++j)
      tile[ty + j * 8][tx] = W[(size_t)(r0 + ty + j * 8) * fo + (c0 + tx)];
    __syncthreads();
#pragma unroll
    for (int j = 0; j < 4; ++j)
      Wt[(size_t)(c0 + ty + j * 8) * fi + (r0 + tx)] = f2bf(tile[tx][ty + j * 8]);
  }
}

// ---- gather-sum per (b,k); float4 loads, 4 groups x 64 lanes, 4 rows in flight ----
__global__ __launch_bounds__(256) void aggregate2_kernel(const float* __restrict__ hs,
                                                         const int* __restrict__ idx,
                                                         const int* __restrict__ off,
                                                         const int* __restrict__ cnt,
                                                         const int* __restrict__ nptr,
                                                         ushort* __restrict__ X,
                                                         int K, int M, int Mpad) {
  int b = blockIdx.x / K, k = blockIdx.x % K;
  int t = threadIdx.x;
  int g = t >> 6, l = t & 63;
  int n = *nptr;
  int c = cnt[b * K + k];
  int o = off[b * K + k];
  const float* hsb = hs + (size_t)b * NTOK * HD;
  const int* ids = idx + (size_t)b * NTOK + o;
  __shared__ int sid[256];
  __shared__ float part[4][HD];
  float a0x = 0.f, a0y = 0.f, a0z = 0.f, a0w = 0.f;
  float a1x = 0.f, a1y = 0.f, a1z = 0.f, a1w = 0.f;
  float a2x = 0.f, a2y = 0.f, a2z = 0.f, a2w = 0.f;
  float a3x = 0.f, a3y = 0.f, a3z = 0.f, a3w = 0.f;
  for (int j0 = 0; j0 < c; j0 += 256) {
    __syncthreads();
    if (j0 + t < c) sid[t] = ids[j0 + t];
    __syncthreads();
    int lim = min(256, c - j0);
    int j = g;
    for (; j + 12 < lim; j += 16) {
      float4 v0 = ((const float4*)&hsb[(size_t)sid[j] * HD])[l];
      float4 v1 = ((const float4*)&hsb[(size_t)sid[j + 4] * HD])[l];
      float4 v2 = ((const float4*)&hsb[(size_t)sid[j + 8] * HD])[l];
      float4 v3 = ((const float4*)&hsb[(size_t)sid[j + 12] * HD])[l];
      a0x += v0.x; a0y += v0.y; a0z += v0.z; a0w += v0.w;
      a1x += v1.x; a1y += v1.y; a1z += v1.z; a1w += v1.w;
      a2x += v2.x; a2y += v2.y; a2z += v2.z; a2w += v2.w;
      a3x += v3.x; a3y += v3.y; a3z += v3.z; a3w += v3.w;
    }
    for (; j < lim; j += 4) {
      float4 v = ((const float4*)&hsb[(size_t)sid[j] * HD])[l];
      a0x += v.x; a0y += v.y; a0z += v.z; a0w += v.w;
    }
  }
  part[g][l * 4 + 0] = (a0x + a1x) + (a2x + a3x);
  part[g][l * 4 + 1] = (a0y + a1y) + (a2y + a3y);
  part[g][l * 4 + 2] = (a0z + a1z) + (a2z + a3z);
  part[g][l * 4 + 3] = (a0w + a1w) + (a2w + a3w);
  __syncthreads();
  float sum = ((part[0][t] + part[1][t]) + (part[2][t] + part[3][t]));
  float hn = hsb[(size_t)n * HD + t];
  int R = 2 * K + 1;
  X[((size_t)b * R + k) * HD + t]     = f2bf(sum);
  X[((size_t)b * R + K + k) * HD + t] = f2bf(sum + hn);
  if (k == 0) {
    X[((size_t)b * R + 2 * K) * HD + t] = f2bf(hn);
    for (int r = M + b; r < Mpad; r += BATCH) X[(size_t)r * HD + t] = 0;
  }
}

// ---- one MLP layer: 96x(NN*32) tile, 2-phase dbuf (round-7 proven structure) ----
template <int NN, bool LAST>
__device__ __forceinline__ void gemm_layer(const ushort* __restrict__ A,
                                           const ushort* __restrict__ Bt,
                                           const float* __restrict__ bias,
                                           const float* __restrict__ aptr,
                                           void* __restrict__ Cout,
                                           int N, int Kd,
                                           ushort* As, ushort* Bs) {
  int tid = threadIdx.x;
  int lane = tid & 63, w = tid >> 6;
  int wr = w >> 1, wc = w & 1;
  int fr = lane & 15, fq = lane >> 4;

  int nwg = gridDim.x;
  int flat = blockIdx.x;
  int q8 = nwg >> 3, r8 = nwg & 7;
  int xcd = flat & 7, loc = flat >> 3;
  int swz = (xcd < r8 ? xcd * (q8 + 1) : r8 * (q8 + 1) + (xcd - r8) * q8) + loc;
  int NC = N / (NN * 32);
  int brow = swz / NC, bcol = swz % NC;

  size_t row0 = (size_t)brow * 96;
  size_t col0 = (size_t)bcol * (NN * 32);

  const ushort* Abase = A + row0 * (size_t)Kd;
  const ushort* Bbase = Bt + col0 * (size_t)Kd;

  f32x4 acc[3][NN] = {};

  int qA0 = w * 64 + lane;
  int qA1 = 256 + w * 64 + lane;  // only waves 0,1
  int rA0 = qA0 >> 2, kA0 = (qA0 & 3) * 8;
  int rA1 = qA1 >> 2, kA1 = (qA1 & 3) * 8;
  int rB = qA0 >> 2, kB = (qA0 & 3) * 8;

  auto stage = [&](int buf, int k0) {
#pragma unroll
    for (int h = 0; h < 2; ++h) {
      int kh = k0 + h * 32;
      gload_lds16(Abase + (size_t)rA0 * Kd + kh + kA0, As + (buf * 2 + h) * (96 * 32) + (w * 64) * 8);
      if (w < 2)
        gload_lds16(Abase + (size_t)rA1 * Kd + kh + kA1, As + (buf * 2 + h) * (96 * 32) + (256 + w * 64) * 8);
      if (NN == 2) {
        gload_lds16(Bbase + (size_t)rB * Kd + kh + kB, Bs + (buf * 2 + h) * (64 * 32) + (w * 64) * 8);
      } else {
        if (w < 2)
          gload_lds16(Bbase + (size_t)rB * Kd + kh + kB, Bs + (buf * 2 + h) * (64 * 32) + (w * 64) * 8);
      }
    }
  };

  int nt = Kd >> 6;
  int cur = 0;
  stage(0, 0);
  __syncthreads();
  for (int t = 0; t < nt; ++t) {
    if (t + 1 < nt) stage(cur ^ 1, (t + 1) * 64);
    bf16x8 af[2][3], bfv[2][NN];
#pragma unroll
    for (int h = 0; h < 2; ++h) {
#pragma unroll
      for (int m = 0; m < 3; ++m)
        af[h][m] = *(const bf16x8*)&As[(cur * 2 + h) * (96 * 32) + (wr * 48 + m * 16 + fr) * 32 + fq * 8];
#pragma unroll
      for (int nn = 0; nn < NN; ++nn)
        bfv[h][nn] = *(const bf16x8*)&Bs[(cur * 2 + h) * (64 * 32) + (wc * (NN * 16) + nn * 16 + fr) * 32 + fq * 8];
    }
#pragma unroll
    for (int h = 0; h < 2; ++h)
#pragma unroll
      for (int m = 0; m < 3; ++m)
#pragma unroll
        for (int nn = 0; nn < NN; ++nn)
          acc[m][nn] = __builtin_amdgcn_mfma_f32_16x16x32_bf16(af[h][m], bfv[h][nn], acc[m][nn], 0, 0, 0);
    __syncthreads();
    cur ^= 1;
  }

  float alpha = 0.f;
  if (!LAST) alpha = aptr[0];
#pragma unroll
  for (int nn = 0; nn < NN; ++nn) {
    size_t col = col0 + wc * (NN * 16) + nn * 16 + fr;
    float bv = bias[col];
#pragma unroll
    for (int m = 0; m < 3; ++m) {
      size_t rbase = row0 + wr * 48 + m * 16 + fq * 4;
#pragma unroll
      for (int j = 0; j < 4; ++j) {
        float v = acc[m][nn][j] + bv;
        if (!LAST) {
          v = (v >= 0.f) ? v : alpha * v;
          ((ushort*)Cout)[(rbase + j) * N + col] = f2bf(v);
        } else {
          ((float*)Cout)[(rbase + j) * N + col] = v;
        }
      }
    }
  }
}

// ---- standalone GEMM kernel (fallback path; identical to round-7) ----
template <int NN, bool LAST>
__global__ __launch_bounds__(256, 4) void gemm_kernel(const ushort* __restrict__ A,
                                                      const ushort* __restrict__ Bt,
                                                      const float* __restrict__ bias,
                                                      const float* __restrict__ aptr,
                                                      void* __restrict__ Cout,
                                                      int N, int Kd) {
  __shared__ ushort As[2 * 2 * 96 * 32];
  __shared__ ushort Bs[2 * 2 * 64 * 32];
  gemm_layer<NN, LAST>(A, Bt, bias, aptr, Cout, N, Kd, As, Bs);
}

// ---- standalone final combine (fallback path) ----
__global__ __launch_bounds__(256) void final_kernel(const float* __restrict__ gs,
                                                    const int* __restrict__ counts,
                                                    const int* __restrict__ Ks,
                                                    float* __restrict__ out,
                                                    int K) {
  int b = blockIdx.x >> 1, half = blockIdx.x & 1;
  int t = threadIdx.x;
  int col = half * 256 + t;
  __shared__ float mk[64];
  __shared__ int sks;
  if (t < K) mk[t] = (counts[b * K + t] > 0) ? 1.f : 0.f;
  if (t == 0) sks = Ks[b];
  __syncthreads();
  int ks = sks;
  bool need = (ks >= 0) && (ks < K - 1);
  const float* g = gs + (size_t)b * (2 * K + 1) * GD;
  float S0 = 0.f;
  for (int k = 0; k < K; ++k) S0 += g[(size_t)k * GD + col] * mk[k];
  float gl0 = S0 + g[(size_t)(2 * K) * GD + col];
  float* G  = out + (size_t)b * (K + 1) * GD;
  float* Gm = out + (size_t)BATCH * (K + 1) * GD + (size_t)b * (K + 1);
  for (int kk = 0; kk <= K; ++kk) {
    float v0;
    if (kk == K)                   v0 = need ? 0.f : gl0;
    else if (need && kk == ks + 1) v0 = gl0;
    else v0 = mk[kk] * (S0 - g[(size_t)kk * GD + col] + g[(size_t)(K + kk) * GD + col]);
    G[(size_t)kk * GD + col] = v0;
  }
  if (half == 0 && t <= K) Gm[t] = (need && t >= ks + 2) ? 0.f : 1.f;
}

// ---- sense-reversing grid barrier (requires co-residency: cooperative launch) ----
__device__ __forceinline__ void grid_barrier(int* cnt, int* gen) {
  __threadfence();          // each thread's writes drained to device scope
  __syncthreads();          // block-level ordering before tid0 signals
  if (threadIdx.x == 0) {
    int g = atomicAdd(gen, 0);                 // read generation BEFORE arriving
    if (atomicAdd(cnt, 1) == (int)gridDim.x - 1) {
      atomicExch(cnt, 0);
      __threadfence();
      atomicAdd(gen, 1);                       // release
    } else {
      while (atomicAdd(gen, 0) == g) {}        // spin (device-scope RMW load)
    }
    __threadfence();                           // acquire
  }
  __syncthreads();
}

struct MLPArgs {
  const ushort* X;
  ushort* Y0;
  ushort* Y1;
  float* gsb;
  const ushort* Wt[6];
  const float* bias[6];
  const float* aptr[5];
  const int* counts;
  const int* Ks;
  float* out;
  int K;
  int* bar;  // [0]=cnt, [1]=gen (zeroed per launch)
};

// ---- all 6 MLP layers + final combine in one cooperative kernel ----
__global__ __launch_bounds__(256, 4) void mlp_fused(MLPArgs a) {
  __shared__ ushort As[2 * 2 * 96 * 32];  // 24 KB
  __shared__ ushort Bs[2 * 2 * 64 * 32];  // 16 KB
  __shared__ int sksh;
  int* cnt = a.bar;
  int* gen = a.bar + 1;

  gemm_layer<2, false>(a.X,  a.Wt[0], a.bias[0], a.aptr[0], (void*)a.Y0, HDIM, HD,   As, Bs);
  grid_barrier(cnt, gen);
  gemm_layer<2, false>(a.Y0, a.Wt[1], a.bias[1], a.aptr[1], (void*)a.Y1, HDIM, HDIM, As, Bs);
  grid_barrier(cnt, gen);
  gemm_layer<2, false>(a.Y1, a.Wt[2], a.bias[2], a.aptr[2], (void*)a.Y0, HDIM, HDIM, As, Bs);
  grid_barrier(cnt, gen);
  gemm_layer<2, false>(a.Y0, a.Wt[3], a.bias[3], a.aptr[3], (void*)a.Y1, HDIM, HDIM, As, Bs);
  grid_barrier(cnt, gen);
  gemm_layer<2, false>(a.Y1, a.Wt[4], a.bias[4], a.aptr[4], (void*)a.Y0, HDIM, HDIM, As, Bs);
  grid_barrier(cnt, gen);
  gemm_layer<1, true >(a.Y0, a.Wt[5], a.bias[5], nullptr,   (void*)a.gsb, GD, HDIM,  As, Bs);
  grid_barrier(cnt, gen);

  // ---- final combine on blocks [0, 2*BATCH) ----
  if (blockIdx.x < 2 * BATCH) {
    int K = a.K;
    int b = blockIdx.x >> 1, half = blockIdx.x & 1;
    int t = threadIdx.x;
    int col = half * 256 + t;
    float* mk = (float*)As;  // reuse dead LDS
    if (t < K) mk[t] = (a.counts[b * K + t] > 0) ? 1.f : 0.f;
    if (t == 0) sksh = a.Ks[b];
    __syncthreads();
    int ks = sksh;
    bool need = (ks >= 0) && (ks < K - 1);
    const float* g = a.gsb + (size_t)b * (2 * K + 1) * GD;
    float S0 = 0.f;
    for (int k = 0; k < K; ++k) S0 += g[(size_t)k * GD + col] * mk[k];
    float gl0 = S0 + g[(size_t)(2 * K) * GD + col];
    float* G  = a.out + (size_t)b * (K + 1) * GD;
    float* Gm = a.out + (size_t)BATCH * (K + 1) * GD + (size_t)b * (K + 1);
    for (int kk = 0; kk <= K; ++kk) {
      float v0;
      if (kk == K)                   v0 = need ? 0.f : gl0;
      else if (need && kk == ks + 1) v0 = gl0;
      else v0 = mk[kk] * (S0 - g[(size_t)kk * GD + col] + g[(size_t)(K + kk) * GD + col]);
      G[(size_t)kk * GD + col] = v0;
    }
    if (half == 0 && t <= K) Gm[t] = (need && t >= ks + 2) ? 0.f : 1.f;
  }
}

extern "C" void kernel_launch(void* const* d_in, const int* in_sizes, int n_in,
                              void* d_out, int out_size, void* d_ws, size_t ws_size,
                              hipStream_t stream) {
  const float* hs = (const float*)d_in[0];
  const float* W[6]  = {(const float*)d_in[1], (const float*)d_in[4], (const float*)d_in[7],
                        (const float*)d_in[10], (const float*)d_in[13], (const float*)d_in[16]};
  const float* bb[6] = {(const float*)d_in[2], (const float*)d_in[5], (const float*)d_in[8],
                        (const float*)d_in[11], (const float*)d_in[14], (const float*)d_in[17]};
  const float* aa[5] = {(const float*)d_in[3], (const float*)d_in[6], (const float*)d_in[9],
                        (const float*)d_in[12], (const float*)d_in[15]};
  const int* cs   = (const int*)d_in[18];
  const int* nptr = (const int*)d_in[19];
  float* out = (float*)d_out;

  int K = out_size / (BATCH * (GD + 1)) - 1;  // 32
  int M = BATCH * (2 * K + 1);                // 4160
  int Mpad = (M + 95) / 96 * 96;              // 4224 (44 tiles of 96)

  char* base = (char*)d_ws;
  size_t off_b = 0;
  auto alloc = [&](size_t bytes) {
    char* p = base + off_b;
    off_b = (off_b + bytes + 255) & ~(size_t)255;
    return p;
  };
  ushort* W1t  = (ushort*)alloc((size_t)HDIM * HD * 2);
  ushort* W2t  = (ushort*)alloc((size_t)HDIM * HDIM * 2);
  ushort* W3t  = (ushort*)alloc((size_t)HDIM * HDIM * 2);
  ushort* W4t  = (ushort*)alloc((size_t)HDIM * HDIM * 2);
  ushort* W5bt = (ushort*)alloc((size_t)HDIM * HDIM * 2);
  ushort* W6t  = (ushort*)alloc((size_t)GD * HDIM * 2);
  int* idx     = (int*)alloc((size_t)BATCH * NTOK * 4);
  int* offb    = (int*)alloc((size_t)BATCH * K * 4);
  int* cntb    = (int*)alloc((size_t)BATCH * K * 4);
  int* Ksb     = (int*)alloc(BATCH * 4);
  ushort* X    = (ushort*)alloc((size_t)Mpad * HD * 2);
  ushort* Y0   = (ushort*)alloc((size_t)Mpad * HDIM * 2);
  ushort* Y1   = (ushort*)alloc((size_t)Mpad * HDIM * 2);
  float*  gsb  = (float*)alloc((size_t)Mpad * GD * 4);
  int* bar     = (int*)alloc(256);
  (void)ws_size; (void)n_in; (void)in_sizes;

  WTArgs wa;
  wa.src[0] = W[0]; wa.dst[0] = W1t;  wa.fi[0] = HD;   wa.fo[0] = HDIM;
  wa.src[1] = W[1]; wa.dst[1] = W2t;  wa.fi[1] = HDIM; wa.fo[1] = HDIM;
  wa.src[2] = W[2]; wa.dst[2] = W3t;  wa.fi[2] = HDIM; wa.fo[2] = HDIM;
  wa.src[3] = W[3]; wa.dst[3] = W4t;  wa.fi[3] = HDIM; wa.fo[3] = HDIM;
  wa.src[4] = W[4]; wa.dst[4] = W5bt; wa.fi[4] = HDIM; wa.fo[4] = HDIM;
  wa.src[5] = W[5]; wa.dst[5] = W6t;  wa.fi[5] = HDIM; wa.fo[5] = GD;
  int nbw = 0;
  for (int z = 0; z < 6; ++z) nbw += (wa.fo[z] / 32) * (wa.fi[z] / 32);
  hipLaunchKernelGGL(pre_kernel, dim3(BATCH + nbw), dim3(256), 0, stream,
                     wa, cs, nptr, idx, offb, cntb, Ksb, K);

  hipLaunchKernelGGL(aggregate2_kernel, dim3(BATCH * K), dim3(256), 0, stream,
                     hs, idx, offb, cntb, nptr, X, K, M, Mpad);

  int NR = Mpad / 96;            // 44
  int ngrid = NR * (HDIM / 64);  // 704 (== NR * GD/32 for the last layer)
  dim3 blk(256);

  // barrier state must start zeroed every call (cnt self-resets; memset is idempotent)
  hipMemsetAsync(bar, 0, 8, stream);

  MLPArgs ma;
  ma.X = X; ma.Y0 = Y0; ma.Y1 = Y1; ma.gsb = gsb;
  ma.Wt[0] = W1t; ma.Wt[1] = W2t; ma.Wt[2] = W3t;
  ma.Wt[3] = W4t; ma.Wt[4] = W5bt; ma.Wt[5] = W6t;
  for (int i = 0; i < 6; ++i) ma.bias[i] = bb[i];
  for (int i = 0; i < 5; ++i) ma.aptr[i] = aa[i];
  ma.counts = cntb; ma.Ks = Ksb; ma.out = out; ma.K = K;
  ma.bar = bar;
  void* kargs[] = {(void*)&ma};
  hipError_t err = hipLaunchCooperativeKernel((const void*)mlp_fused, dim3(ngrid), dim3(256),
                                              kargs, 0, stream);
  if (err != hipSuccess) {
    (void)hipGetLastError();  // clear sticky error; take the proven 7-dispatch path
    hipLaunchKernelGGL((gemm_kernel<2, false>), dim3(ngrid), blk, 0, stream, X,   W1t,  bb[0], aa[0], (void*)Y0, HDIM, HD);
    hipLaunchKernelGGL((gemm_kernel<2, false>), dim3(ngrid), blk, 0, stream, Y0,  W2t,  bb[1], aa[1], (void*)Y1, HDIM, HDIM);
    hipLaunchKernelGGL((gemm_kernel<2, false>), dim3(ngrid), blk, 0, stream, Y1,  W3t,  bb[2], aa[2], (void*)Y0, HDIM, HDIM);
    hipLaunchKernelGGL((gemm_kernel<2, false>), dim3(ngrid), blk, 0, stream, Y0,  W4t,  bb[3], aa[3], (void*)Y1, HDIM, HDIM);
    hipLaunchKernelGGL((gemm_kernel<2, false>), dim3(ngrid), blk, 0, stream, Y1,  W5bt, bb[4], aa[4], (void*)Y0, HDIM, HDIM);
    hipLaunchKernelGGL((gemm_kernel<1, true>),  dim3(ngrid), blk, 0, stream, Y0,  W6t,  bb[5], nullptr, (void*)gsb, GD, HDIM);
    hipLaunchKernelGGL(final_kernel, dim3(BATCH * 2), dim3(256), 0, stream, gsb, cntb, Ksb, out, K);
  }
}

// Round 11
// 134.843 us; speedup vs baseline: 7.3520x; 7.3520x over previous
//
#include <hip/hip_runtime.h>
#include <hip/hip_bf16.h>
#include <stdint.h>

using bf16x8 = __attribute__((ext_vector_type(8))) short;
using f32x4  = __attribute__((ext_vector_type(4))) float;

#define BATCH 64
#define NTOK  4096
#define HD    256
#define HDIM  1024
#define GD    512

__device__ __forceinline__ ushort f2bf(float f) {
  union { __hip_bfloat16 h; ushort u; } cv;
  cv.h = __float2bfloat16(f);
  return cv.u;
}

__device__ __forceinline__ void gload_lds16(const void* gsrc, void* ldst) {
  typedef const __attribute__((address_space(1))) uint32_t* gas_p;
  typedef __attribute__((address_space(3))) uint32_t* las_p;
  __builtin_amdgcn_global_load_lds((gas_p)(uintptr_t)gsrc, (las_p)(uintptr_t)ldst, 16, 0, 0);
}

struct WTArgs {
  const float* src[6];
  ushort* dst[6];
  int fi[6];
  int fo[6];
};

// ---- merged pre-pass: blocks [0,64) = bucket per batch; rest = weight transposes ----
__global__ __launch_bounds__(256) void pre_kernel(WTArgs a,
                                                  const int* __restrict__ cs,
                                                  const int* __restrict__ nptr,
                                                  int* __restrict__ idx,
                                                  int* __restrict__ off,
                                                  int* __restrict__ cnt,
                                                  int* __restrict__ Ks,
                                                  int K) {
  __shared__ int csb[NTOK];
  __shared__ ushort hist[256 * 32];
  __shared__ int segsum[8][32];
  __shared__ int btot[32];
  __shared__ int bbase[32];
  __shared__ int red[4];
  __shared__ float tile[32][33];
  int t = threadIdx.x;
  if (blockIdx.x < BATCH) {
    int b = blockIdx.x;
    int n = *nptr;
    const int* csrow = cs + (size_t)b * NTOK;
    int mymax = -1;
    for (int i = t; i < n; i += 256) { int v = csrow[i]; csb[i] = v; mymax = max(mymax, v); }
#pragma unroll
    for (int k = 0; k < 32; ++k) hist[t * 32 + k] = 0;
    __syncthreads();
    int chunkN = (n + 255) >> 8;
    for (int c = 0; c < chunkN; ++c) {
      int i = c * 256 + t;
      if (i < n) hist[t * 32 + csb[i]]++;
    }
    __syncthreads();
    int kb = t & 31, sg = t >> 5;
    {
      int run = 0;
      int r0 = sg * 32;
      for (int r = r0; r < r0 + 32; ++r) run += hist[r * 32 + kb];
      segsum[sg][kb] = run;
    }
    __syncthreads();
    if (t < 32) {
      int acc0 = 0;
      for (int s = 0; s < 8; ++s) { int v = segsum[s][t]; segsum[s][t] = acc0; acc0 += v; }
      btot[t] = acc0;
    }
    __syncthreads();
    {
      int run = segsum[sg][kb];
      int r0 = sg * 32;
      for (int r = r0; r < r0 + 32; ++r) {
        int tmp = hist[r * 32 + kb];
        hist[r * 32 + kb] = (ushort)run;
        run += tmp;
      }
    }
    if (t == 0) {
      int base = 0;
      for (int k = 0; k < K; ++k) { bbase[k] = base; base += btot[k]; }
    }
    __syncthreads();
    if (t < K) { off[b * K + t] = bbase[t]; cnt[b * K + t] = btot[t]; }
    int* idxb = idx + (size_t)b * NTOK;
    for (int c = 0; c < chunkN; ++c) {
      int i = c * 256 + t;
      if (i < n) {
        int k = csb[i];
        int s = bbase[k] + (int)(hist[t * 32 + k]++);
        idxb[s] = i;
      }
    }
    for (int o2 = 32; o2; o2 >>= 1) mymax = max(mymax, __shfl_down(mymax, o2));
    if ((t & 63) == 0) red[t >> 6] = mymax;
    __syncthreads();
    if (t == 0) {
      int r = red[0];
      for (int i = 1; i < 4; ++i) r = max(r, red[i]);
      Ks[b] = r;
    }
  } else {
    int f = blockIdx.x - BATCH;
    int z = 0;
    while (true) {
      int nb = (a.fo[z] >> 5) * (a.fi[z] >> 5);
      if (f < nb) break;
      f -= nb; ++z;
    }
    int ncx = a.fo[z] >> 5;
    int cx = f % ncx, cy = f / ncx;
    int c0 = cx * 32, r0 = cy * 32;
    int fo = a.fo[z], fi = a.fi[z];
    const float* W = a.src[z];
    ushort* Wt = a.dst[z];
    int tx = t & 31, ty = t >> 5;
#pragma unroll
    for (int j = 0; j < 4; ++j)
      tile[ty + j * 8][tx] = W[(size_t)(r0 + ty + j * 8) * fo + (c0 + tx)];
    __syncthreads();
#pragma unroll
    for (int j = 0; j < 4; ++j)
      Wt[(size_t)(c0 + ty + j * 8) * fi + (r0 + tx)] = f2bf(tile[tx][ty + j * 8]);
  }
}

// ---- gather-sum per (b,k); float4 loads, 4 groups x 64 lanes, 4 rows in flight ----
__global__ __launch_bounds__(256) void aggregate2_kernel(const float* __restrict__ hs,
                                                         const int* __restrict__ idx,
                                                         const int* __restrict__ off,
                                                         const int* __restrict__ cnt,
                                                         const int* __restrict__ nptr,
                                                         ushort* __restrict__ X,
                                                         int K, int M, int Mpad) {
  int b = blockIdx.x / K, k = blockIdx.x % K;
  int t = threadIdx.x;
  int g = t >> 6, l = t & 63;
  int n = *nptr;
  int c = cnt[b * K + k];
  int o = off[b * K + k];
  const float* hsb = hs + (size_t)b * NTOK * HD;
  const int* ids = idx + (size_t)b * NTOK + o;
  __shared__ int sid[256];
  __shared__ float part[4][HD];
  float a0x = 0.f, a0y = 0.f, a0z = 0.f, a0w = 0.f;
  float a1x = 0.f, a1y = 0.f, a1z = 0.f, a1w = 0.f;
  float a2x = 0.f, a2y = 0.f, a2z = 0.f, a2w = 0.f;
  float a3x = 0.f, a3y = 0.f, a3z = 0.f, a3w = 0.f;
  for (int j0 = 0; j0 < c; j0 += 256) {
    __syncthreads();
    if (j0 + t < c) sid[t] = ids[j0 + t];
    __syncthreads();
    int lim = min(256, c - j0);
    int j = g;
    for (; j + 12 < lim; j += 16) {
      float4 v0 = ((const float4*)&hsb[(size_t)sid[j] * HD])[l];
      float4 v1 = ((const float4*)&hsb[(size_t)sid[j + 4] * HD])[l];
      float4 v2 = ((const float4*)&hsb[(size_t)sid[j + 8] * HD])[l];
      float4 v3 = ((const float4*)&hsb[(size_t)sid[j + 12] * HD])[l];
      a0x += v0.x; a0y += v0.y; a0z += v0.z; a0w += v0.w;
      a1x += v1.x; a1y += v1.y; a1z += v1.z; a1w += v1.w;
      a2x += v2.x; a2y += v2.y; a2z += v2.z; a2w += v2.w;
      a3x += v3.x; a3y += v3.y; a3z += v3.z; a3w += v3.w;
    }
    for (; j < lim; j += 4) {
      float4 v = ((const float4*)&hsb[(size_t)sid[j] * HD])[l];
      a0x += v.x; a0y += v.y; a0z += v.z; a0w += v.w;
    }
  }
  part[g][l * 4 + 0] = (a0x + a1x) + (a2x + a3x);
  part[g][l * 4 + 1] = (a0y + a1y) + (a2y + a3y);
  part[g][l * 4 + 2] = (a0z + a1z) + (a2z + a3z);
  part[g][l * 4 + 3] = (a0w + a1w) + (a2w + a3w);
  __syncthreads();
  float sum = ((part[0][t] + part[1][t]) + (part[2][t] + part[3][t]));
  float hn = hsb[(size_t)n * HD + t];
  int R = 2 * K + 1;
  X[((size_t)b * R + k) * HD + t]     = f2bf(sum);
  X[((size_t)b * R + K + k) * HD + t] = f2bf(sum + hn);
  if (k == 0) {
    X[((size_t)b * R + 2 * K) * HD + t] = f2bf(hn);
    for (int r = M + b; r < Mpad; r += BATCH) X[(size_t)r * HD + t] = 0;
  }
}

// ---- 96x(NN*32) bf16 MFMA GEMM, 2-phase dbuf (r7 structure) + LDS bank swizzle ----
// Swizzle (both-sides bijection, rule #21): within each 1KB block (16 rows x 4
// 16B-chunks), logical (a,c) lives at physical chunk
//   P(a,c) = (a>>1)<<3 | (a&1)<<2 | (c ^ ((a>>1)&3))
// gload_lds dest stays linear; the per-lane GLOBAL source is pre-swizzled with
// the inverse map; ds_reads use P(fr,fq). Each 16-lane read group then touches
// all 8 bank-quads exactly twice (free 2-way) instead of 2 quads (8-way).
template <int NN, bool LAST>
__global__ __launch_bounds__(256, 4) void gemm_kernel(const ushort* __restrict__ A,
                                                      const ushort* __restrict__ Bt,
                                                      const float* __restrict__ bias,
                                                      const float* __restrict__ aptr,
                                                      void* __restrict__ Cout,
                                                      int N, int Kd) {
  __shared__ ushort As[2][2][96 * 32];       // 24 KB
  __shared__ ushort Bs[2][2][NN * 32 * 32];  // 16 KB (NN=2) / 8 KB (NN=1)
  int tid = threadIdx.x;
  int lane = tid & 63, w = tid >> 6;
  int wr = w >> 1, wc = w & 1;          // wave grid 2x2: rows wr*48, cols wc*(NN*16)
  int fr = lane & 15, fq = lane >> 4;

  // bijective XCD swizzle (m204); col-fast decomposition
  int nwg = gridDim.x;
  int flat = blockIdx.x;
  int q8 = nwg >> 3, r8 = nwg & 7;
  int xcd = flat & 7, loc = flat >> 3;
  int swz = (xcd < r8 ? xcd * (q8 + 1) : r8 * (q8 + 1) + (xcd - r8) * q8) + loc;
  int NC = N / (NN * 32);
  int brow = swz / NC, bcol = swz % NC;

  size_t row0 = (size_t)brow * 96;
  size_t col0 = (size_t)bcol * (NN * 32);

  const ushort* Abase = A + row0 * (size_t)Kd;
  const ushort* Bbase = Bt + col0 * (size_t)Kd;

  f32x4 acc[3][NN] = {};

  // ---- staging source pre-swizzle: lane `pl` of a block-aligned gload holds
  // physical chunk pl -> logical row a_swz, k-chunk c_swz (inverse of P)
  int pl = lane;
  int a_swz = ((pl >> 3) << 1) | ((pl >> 2) & 1);
  int c8 = ((pl & 3) ^ ((pl >> 3) & 3)) * 8;
  const ushort* srcA0 = Abase + (size_t)(w * 16 + a_swz) * Kd + c8;        // blocks 0..3
  const ushort* srcA1 = Abase + (size_t)((4 + w) * 16 + a_swz) * Kd + c8;  // blocks 4,5 (w<2)
  const ushort* srcB  = Bbase + (size_t)(w * 16 + a_swz) * Kd + c8;

  auto stage = [&](int buf, int k0) {
#pragma unroll
    for (int h = 0; h < 2; ++h) {
      int kh = k0 + h * 32;
      gload_lds16(srcA0 + kh, &As[buf][h][(w * 64) * 8]);
      if (w < 2)
        gload_lds16(srcA1 + kh, &As[buf][h][(256 + w * 64) * 8]);
      if (NN == 2) {
        gload_lds16(srcB + kh, &Bs[buf][h][(w * 64) * 8]);
      } else {
        if (w < 2)
          gload_lds16(srcB + kh, &Bs[buf][h][(w * 64) * 8]);
      }
    }
  };

  // ---- read-side swizzled chunk offset (ushort units): P(fr,fq)*8
  int Pl8 = (((fr >> 1) << 3) | ((fr & 1) << 2) | (fq ^ ((fr >> 1) & 3))) * 8;

  int nt = Kd >> 6;
  int cur = 0;
  stage(0, 0);
  __syncthreads();
  for (int t = 0; t < nt; ++t) {
    if (t + 1 < nt) stage(cur ^ 1, (t + 1) * 64);
    bf16x8 af[2][3], bfv[2][NN];
#pragma unroll
    for (int h = 0; h < 2; ++h) {
#pragma unroll
      for (int m = 0; m < 3; ++m)
        af[h][m] = *(const bf16x8*)&As[cur][h][(wr * 3 + m) * 512 + Pl8];
#pragma unroll
      for (int nn = 0; nn < NN; ++nn)
        bfv[h][nn] = *(const bf16x8*)&Bs[cur][h][(wc * NN + nn) * 512 + Pl8];
    }
#pragma unroll
    for (int h = 0; h < 2; ++h)
#pragma unroll
      for (int m = 0; m < 3; ++m)
#pragma unroll
        for (int nn = 0; nn < NN; ++nn)
          acc[m][nn] = __builtin_amdgcn_mfma_f32_16x16x32_bf16(af[h][m], bfv[h][nn], acc[m][nn], 0, 0, 0);
    __syncthreads();
    cur ^= 1;
  }

  float alpha = 0.f;
  if (!LAST) alpha = aptr[0];
#pragma unroll
  for (int nn = 0; nn < NN; ++nn) {
    size_t col = col0 + wc * (NN * 16) + nn * 16 + fr;
    float bv = bias[col];
#pragma unroll
    for (int m = 0; m < 3; ++m) {
      size_t rbase = row0 + wr * 48 + m * 16 + fq * 4;
#pragma unroll
      for (int j = 0; j < 4; ++j) {
        float v = acc[m][nn][j] + bv;
        if (!LAST) {
          v = (v >= 0.f) ? v : alpha * v;
          ((ushort*)Cout)[(rbase + j) * N + col] = f2bf(v);
        } else {
          ((float*)Cout)[(rbase + j) * N + col] = v;
        }
      }
    }
  }
}

// ---- S, G_head/G_last, Ks move logic, G_mask; 2 blocks per batch (256-col halves) ----
__global__ __launch_bounds__(256) void final_kernel(const float* __restrict__ gs,
                                                    const int* __restrict__ counts,
                                                    const int* __restrict__ Ks,
                                                    float* __restrict__ out,
                                                    int K) {
  int b = blockIdx.x >> 1, half = blockIdx.x & 1;
  int t = threadIdx.x;
  int col = half * 256 + t;
  __shared__ float mk[64];
  __shared__ int sks;
  if (t < K) mk[t] = (counts[b * K + t] > 0) ? 1.f : 0.f;
  if (t == 0) sks = Ks[b];
  __syncthreads();
  int ks = sks;
  bool need = (ks >= 0) && (ks < K - 1);
  const float* g = gs + (size_t)b * (2 * K + 1) * GD;
  float S0 = 0.f;
  for (int k = 0; k < K; ++k) S0 += g[(size_t)k * GD + col] * mk[k];
  float gl0 = S0 + g[(size_t)(2 * K) * GD + col];
  float* G  = out + (size_t)b * (K + 1) * GD;
  float* Gm = out + (size_t)BATCH * (K + 1) * GD + (size_t)b * (K + 1);
  for (int kk = 0; kk <= K; ++kk) {
    float v0;
    if (kk == K)                   v0 = need ? 0.f : gl0;
    else if (need && kk == ks + 1) v0 = gl0;
    else v0 = mk[kk] * (S0 - g[(size_t)kk * GD + col] + g[(size_t)(K + kk) * GD + col]);
    G[(size_t)kk * GD + col] = v0;
  }
  if (half == 0 && t <= K) Gm[t] = (need && t >= ks + 2) ? 0.f : 1.f;
}

extern "C" void kernel_launch(void* const* d_in, const int* in_sizes, int n_in,
                              void* d_out, int out_size, void* d_ws, size_t ws_size,
                              hipStream_t stream) {
  const float* hs = (const float*)d_in[0];
  const float* W[6]  = {(const float*)d_in[1], (const float*)d_in[4], (const float*)d_in[7],
                        (const float*)d_in[10], (const float*)d_in[13], (const float*)d_in[16]};
  const float* bb[6] = {(const float*)d_in[2], (const float*)d_in[5], (const float*)d_in[8],
                        (const float*)d_in[11], (const float*)d_in[14], (const float*)d_in[17]};
  const float* aa[5] = {(const float*)d_in[3], (const float*)d_in[6], (const float*)d_in[9],
                        (const float*)d_in[12], (const float*)d_in[15]};
  const int* cs   = (const int*)d_in[18];
  const int* nptr = (const int*)d_in[19];
  float* out = (float*)d_out;

  int K = out_size / (BATCH * (GD + 1)) - 1;  // 32
  int M = BATCH * (2 * K + 1);                // 4160
  int Mpad = (M + 95) / 96 * 96;              // 4224 (44 tiles of 96)

  char* base = (char*)d_ws;
  size_t off_b = 0;
  auto alloc = [&](size_t bytes) {
    char* p = base + off_b;
    off_b = (off_b + bytes + 255) & ~(size_t)255;
    return p;
  };
  ushort* W1t  = (ushort*)alloc((size_t)HDIM * HD * 2);
  ushort* W2t  = (ushort*)alloc((size_t)HDIM * HDIM * 2);
  ushort* W3t  = (ushort*)alloc((size_t)HDIM * HDIM * 2);
  ushort* W4t  = (ushort*)alloc((size_t)HDIM * HDIM * 2);
  ushort* W5bt = (ushort*)alloc((size_t)HDIM * HDIM * 2);
  ushort* W6t  = (ushort*)alloc((size_t)GD * HDIM * 2);
  int* idx     = (int*)alloc((size_t)BATCH * NTOK * 4);
  int* offb    = (int*)alloc((size_t)BATCH * K * 4);
  int* cntb    = (int*)alloc((size_t)BATCH * K * 4);
  int* Ksb     = (int*)alloc(BATCH * 4);
  ushort* X    = (ushort*)alloc((size_t)Mpad * HD * 2);
  ushort* Y0   = (ushort*)alloc((size_t)Mpad * HDIM * 2);
  ushort* Y1   = (ushort*)alloc((size_t)Mpad * HDIM * 2);
  float*  gsb  = (float*)alloc((size_t)Mpad * GD * 4);
  (void)ws_size; (void)n_in; (void)in_sizes;

  WTArgs wa;
  wa.src[0] = W[0]; wa.dst[0] = W1t;  wa.fi[0] = HD;   wa.fo[0] = HDIM;
  wa.src[1] = W[1]; wa.dst[1] = W2t;  wa.fi[1] = HDIM; wa.fo[1] = HDIM;
  wa.src[2] = W[2]; wa.dst[2] = W3t;  wa.fi[2] = HDIM; wa.fo[2] = HDIM;
  wa.src[3] = W[3]; wa.dst[3] = W4t;  wa.fi[3] = HDIM; wa.fo[3] = HDIM;
  wa.src[4] = W[4]; wa.dst[4] = W5bt; wa.fi[4] = HDIM; wa.fo[4] = HDIM;
  wa.src[5] = W[5]; wa.dst[5] = W6t;  wa.fi[5] = HDIM; wa.fo[5] = GD;
  int nbw = 0;
  for (int z = 0; z < 6; ++z) nbw += (wa.fo[z] / 32) * (wa.fi[z] / 32);
  hipLaunchKernelGGL(pre_kernel, dim3(BATCH + nbw), dim3(256), 0, stream,
                     wa, cs, nptr, idx, offb, cntb, Ksb, K);

  hipLaunchKernelGGL(aggregate2_kernel, dim3(BATCH * K), dim3(256), 0, stream,
                     hs, idx, offb, cntb, nptr, X, K, M, Mpad);

  dim3 blk(256);
  int NR = Mpad / 96;            // 44
  int ngrid = NR * (HDIM / 64);  // 704 (== NR * GD/32 for the last layer)
  hipLaunchKernelGGL((gemm_kernel<2, false>), dim3(ngrid), blk, 0, stream, X,   W1t,  bb[0], aa[0], (void*)Y0, HDIM, HD);
  hipLaunchKernelGGL((gemm_kernel<2, false>), dim3(ngrid), blk, 0, stream, Y0,  W2t,  bb[1], aa[1], (void*)Y1, HDIM, HDIM);
  hipLaunchKernelGGL((gemm_kernel<2, false>), dim3(ngrid), blk, 0, stream, Y1,  W3t,  bb[2], aa[2], (void*)Y0, HDIM, HDIM);
  hipLaunchKernelGGL((gemm_kernel<2, false>), dim3(ngrid), blk, 0, stream, Y0,  W4t,  bb[3], aa[3], (void*)Y1, HDIM, HDIM);
  hipLaunchKernelGGL((gemm_kernel<2, false>), dim3(ngrid), blk, 0, stream, Y1,  W5bt, bb[4], aa[4], (void*)Y0, HDIM, HDIM);
  hipLaunchKernelGGL((gemm_kernel<1, true>),  dim3(ngrid), blk, 0, stream, Y0,  W6t,  bb[5], nullptr, (void*)gsb, GD, HDIM);

  hipLaunchKernelGGL(final_kernel, dim3(BATCH * 2), dim3(256), 0, stream, gsb, cntb, Ksb, out, K);
}